// Round 1
// baseline (1038.469 us; speedup 1.0000x reference)
//
#include <hip/hip_runtime.h>
#include <math.h>

#define B_   8
#define CIN  256
#define L_   1024
#define NH_  8
#define DH_  32

// ---------------------------------------------------------------------------
// 1x1-conv GEMM: out[b,o,l] = sum_c w[o,c] * inp[b,c,l] + bias[o] (+ resid)
// Tile: 64(o) x 64(l), K-chunk 16. Block 256 threads, 4x4 microtile/thread.
// ---------------------------------------------------------------------------
template<int O, bool RES>
__global__ __launch_bounds__(256) void gemm1x1(
    const float* __restrict__ inp, const float* __restrict__ w,
    const float* __restrict__ bias, const float* __restrict__ resid,
    float* __restrict__ out)
{
    __shared__ float Wt[16][68];   // [c][o_local], pad 68 -> float4-aligned, 2-way max
    __shared__ float Xs[16][68];   // [c][l_local]

    const int t  = threadIdx.x;
    const int tx = t & 15, ty = t >> 4;
    const int b  = blockIdx.z;
    const int o0 = blockIdx.y * 64;
    const int l0 = blockIdx.x * 64;

    const float* xb = inp + (size_t)b * CIN * L_;

    const int cl  = t & 15, ol  = t >> 4;   // W-tile load role
    const int ll  = t & 63, cl2 = t >> 6;   // X-tile load role

    float acc[4][4] = {};

    for (int c0 = 0; c0 < CIN; c0 += 16) {
        #pragma unroll
        for (int r = 0; r < 4; r++)
            Wt[cl][ol + r * 16] = w[(size_t)(o0 + ol + r * 16) * CIN + c0 + cl];
        #pragma unroll
        for (int r = 0; r < 4; r++)
            Xs[cl2 + r * 4][ll] = xb[(size_t)(c0 + cl2 + r * 4) * L_ + l0 + ll];
        __syncthreads();

        #pragma unroll
        for (int kc = 0; kc < 16; kc++) {
            const float4 a4 = *(const float4*)&Wt[kc][ty * 4];
            const float4 b4 = *(const float4*)&Xs[kc][tx * 4];
            const float av[4] = {a4.x, a4.y, a4.z, a4.w};
            const float bv[4] = {b4.x, b4.y, b4.z, b4.w};
            #pragma unroll
            for (int i = 0; i < 4; i++)
                #pragma unroll
                for (int j = 0; j < 4; j++)
                    acc[i][j] += av[i] * bv[j];
        }
        __syncthreads();
    }

    #pragma unroll
    for (int i = 0; i < 4; i++) {
        const int o = o0 + ty * 4 + i;
        const float bi = bias[o];
        float4 r4 = make_float4(acc[i][0] + bi, acc[i][1] + bi,
                                acc[i][2] + bi, acc[i][3] + bi);
        const size_t off = ((size_t)b * O + o) * L_ + l0 + tx * 4;
        if (RES) {
            const float4 x4 = *(const float4*)(resid + off);
            r4.x += x4.x; r4.y += x4.y; r4.z += x4.z; r4.w += x4.w;
        }
        *(float4*)(out + off) = r4;
    }
}

// ---------------------------------------------------------------------------
// Fused flash-style attention. One block per (b, head, 64-query tile).
// qkv layout: [b][768][L], q at o=h*32+d, k at 256+..., v at 512+...
// S phase: thread = (wave wv owns rows i=wv*16+ii, lane = column j).
// O phase: thread = (lane = row i, wave wv owns d = wv*8+kk).
// Online softmax, row state replicated per-wave in registers.
// ---------------------------------------------------------------------------
__global__ __launch_bounds__(256) void attn_kern(
    const float* __restrict__ qkv, float* __restrict__ out)
{
    __shared__ float Qs[64][36];   // [i][d] * scale
    __shared__ float Ks[32][64];   // [d][j]
    __shared__ float Vs[64][36];   // [j][d]
    __shared__ float Ss[64][65];   // [i][j]  P-tile
    __shared__ float alpha_s[64];
    __shared__ float l_s[64];

    const int t    = threadIdx.x;
    const int lane = t & 63;
    const int wv   = t >> 6;
    const int b  = blockIdx.z;
    const int h  = blockIdx.y;
    const int i0 = blockIdx.x * 64;

    const float scale = 0.17677669529663687f;  // 1/sqrt(32)

    const float* qb = qkv + ((size_t)b * 768 + h * DH_) * L_;
    const float* kb = qb + (size_t)256 * L_;
    const float* vb = qb + (size_t)512 * L_;

    // Load Q tile (scaled). Coalesced along i.
    #pragma unroll
    for (int r = 0; r < 8; r++) {
        const int d = wv + r * 4;
        Qs[lane][d] = qb[(size_t)d * L_ + i0 + lane] * scale;
    }

    float m_r[16], l_r[16];
    #pragma unroll
    for (int ii = 0; ii < 16; ii++) { m_r[ii] = -INFINITY; l_r[ii] = 0.f; }
    float o_acc[8];
    #pragma unroll
    for (int kk = 0; kk < 8; kk++) o_acc[kk] = 0.f;

    for (int j0 = 0; j0 < L_; j0 += 64) {
        __syncthreads();   // previous O-phase done reading Ks/Vs/Ss/alpha_s
        #pragma unroll
        for (int r = 0; r < 8; r++) {
            const int d = wv + r * 4;
            const float kvv = kb[(size_t)d * L_ + j0 + lane];
            const float vvv = vb[(size_t)d * L_ + j0 + lane];
            Ks[d][lane] = kvv;
            Vs[lane][d] = vvv;
        }
        __syncthreads();

        // ---- S = Q K^T for this tile; thread holds column j=lane ----
        float kreg[32];
        #pragma unroll
        for (int d = 0; d < 32; d++) kreg[d] = Ks[d][lane];

        float p[16];
        #pragma unroll
        for (int ii = 0; ii < 16; ii++) {
            const int i = wv * 16 + ii;
            float s = 0.f;
            #pragma unroll
            for (int d = 0; d < 32; d += 4) {
                const float4 q4 = *(const float4*)&Qs[i][d];
                s += q4.x * kreg[d]     + q4.y * kreg[d + 1]
                   + q4.z * kreg[d + 2] + q4.w * kreg[d + 3];
            }
            p[ii] = s;
        }

        // ---- online softmax per row (row lives across 64 lanes of wave) ----
        #pragma unroll
        for (int ii = 0; ii < 16; ii++) {
            float rm = p[ii];
            rm = fmaxf(rm, __shfl_xor(rm, 32, 64));
            rm = fmaxf(rm, __shfl_xor(rm, 16, 64));
            rm = fmaxf(rm, __shfl_xor(rm,  8, 64));
            rm = fmaxf(rm, __shfl_xor(rm,  4, 64));
            rm = fmaxf(rm, __shfl_xor(rm,  2, 64));
            rm = fmaxf(rm, __shfl_xor(rm,  1, 64));
            const float mn = fmaxf(m_r[ii], rm);
            const float al = __expf(m_r[ii] - mn);   // 0 on first tile (m=-inf)
            m_r[ii] = mn;
            const float pv = __expf(p[ii] - mn);
            float rs = pv;
            rs += __shfl_xor(rs, 32, 64);
            rs += __shfl_xor(rs, 16, 64);
            rs += __shfl_xor(rs,  8, 64);
            rs += __shfl_xor(rs,  4, 64);
            rs += __shfl_xor(rs,  2, 64);
            rs += __shfl_xor(rs,  1, 64);
            l_r[ii] = l_r[ii] * al + rs;
            Ss[wv * 16 + ii][lane] = pv;
            if (lane == 0) alpha_s[wv * 16 + ii] = al;
        }
        __syncthreads();

        // ---- O update: thread = (row i=lane, d = wv*8+kk) ----
        const float al = alpha_s[lane];
        #pragma unroll
        for (int kk = 0; kk < 8; kk++) o_acc[kk] *= al;

        #pragma unroll 4
        for (int j = 0; j < 64; j += 4) {
            const float4 p4 = *(const float4*)&Ss[lane][j];
            const float pj[4] = {p4.x, p4.y, p4.z, p4.w};
            #pragma unroll
            for (int u = 0; u < 4; u++) {
                const float4 v0 = *(const float4*)&Vs[j + u][wv * 8];
                const float4 v1 = *(const float4*)&Vs[j + u][wv * 8 + 4];
                o_acc[0] += pj[u] * v0.x;
                o_acc[1] += pj[u] * v0.y;
                o_acc[2] += pj[u] * v0.z;
                o_acc[3] += pj[u] * v0.w;
                o_acc[4] += pj[u] * v1.x;
                o_acc[5] += pj[u] * v1.y;
                o_acc[6] += pj[u] * v1.z;
                o_acc[7] += pj[u] * v1.w;
            }
        }
    }

    // ---- finalize: broadcast l to O-phase mapping, divide, store ----
    if (lane == 0) {
        #pragma unroll
        for (int ii = 0; ii < 16; ii++) l_s[wv * 16 + ii] = l_r[ii];
    }
    __syncthreads();
    const float inv = 1.f / l_s[lane];
    #pragma unroll
    for (int kk = 0; kk < 8; kk++) {
        const int d = wv * 8 + kk;
        out[((size_t)b * CIN + h * DH_ + d) * L_ + i0 + lane] = o_acc[kk] * inv;
    }
}

// ---------------------------------------------------------------------------
extern "C" void kernel_launch(void* const* d_in, const int* in_sizes, int n_in,
                              void* d_out, int out_size, void* d_ws, size_t ws_size,
                              hipStream_t stream) {
    const float* x      = (const float*)d_in[0];
    const float* w_qkv  = (const float*)d_in[1];
    const float* b_qkv  = (const float*)d_in[2];
    const float* w_proj = (const float*)d_in[3];
    const float* b_proj = (const float*)d_in[4];
    float* out = (float*)d_out;

    float* qkv   = (float*)d_ws;              // 8*768*1024 = 6291456 floats (24 MB)
    float* attno = qkv + (size_t)B_ * 768 * L_; // 8*256*1024 = 2097152 floats (8 MB)

    // QKV projection: [8192,256] x [256,768]
    gemm1x1<768, false><<<dim3(L_ / 64, 768 / 64, B_), 256, 0, stream>>>(
        x, w_qkv, b_qkv, nullptr, qkv);

    // Fused attention
    attn_kern<<<dim3(L_ / 64, NH_, B_), 256, 0, stream>>>(qkv, attno);

    // Output projection + bias + residual
    gemm1x1<256, true><<<dim3(L_ / 64, 256 / 64, B_), 256, 0, stream>>>(
        attno, w_proj, b_proj, x, out);
}

// Round 2
// 205.560 us; speedup vs baseline: 5.0519x; 5.0519x over previous
//
#include <hip/hip_runtime.h>
#include <math.h>

#define B_   8
#define CIN  256
#define L_   1024
#define NH_  8
#define DH_  32

typedef __attribute__((ext_vector_type(8))) short short8;
typedef __attribute__((ext_vector_type(4))) short short4v;
typedef __attribute__((ext_vector_type(4))) float f32x4;

__device__ inline short f2bf(float f) {
    union { float f; unsigned u; } v; v.f = f;
    return (short)((v.u + 0x7FFFu + ((v.u >> 16) & 1u)) >> 16);
}

// ---------------------------------------------------------------------------
// 1x1-conv GEMM (fp32, unchanged from round 1): out[b,o,l] = w[o,:]·inp[b,:,l]
// ---------------------------------------------------------------------------
template<int O, bool RES>
__global__ __launch_bounds__(256) void gemm1x1(
    const float* __restrict__ inp, const float* __restrict__ w,
    const float* __restrict__ bias, const float* __restrict__ resid,
    float* __restrict__ out)
{
    __shared__ float Wt[16][68];
    __shared__ float Xs[16][68];

    const int t  = threadIdx.x;
    const int tx = t & 15, ty = t >> 4;
    const int b  = blockIdx.z;
    const int o0 = blockIdx.y * 64;
    const int l0 = blockIdx.x * 64;

    const float* xb = inp + (size_t)b * CIN * L_;

    const int cl  = t & 15, ol  = t >> 4;
    const int ll  = t & 63, cl2 = t >> 6;

    float acc[4][4] = {};

    for (int c0 = 0; c0 < CIN; c0 += 16) {
        #pragma unroll
        for (int r = 0; r < 4; r++)
            Wt[cl][ol + r * 16] = w[(size_t)(o0 + ol + r * 16) * CIN + c0 + cl];
        #pragma unroll
        for (int r = 0; r < 4; r++)
            Xs[cl2 + r * 4][ll] = xb[(size_t)(c0 + cl2 + r * 4) * L_ + l0 + ll];
        __syncthreads();

        #pragma unroll
        for (int kc = 0; kc < 16; kc++) {
            const float4 a4 = *(const float4*)&Wt[kc][ty * 4];
            const float4 b4 = *(const float4*)&Xs[kc][tx * 4];
            const float av[4] = {a4.x, a4.y, a4.z, a4.w};
            const float bv[4] = {b4.x, b4.y, b4.z, b4.w};
            #pragma unroll
            for (int i = 0; i < 4; i++)
                #pragma unroll
                for (int j = 0; j < 4; j++)
                    acc[i][j] += av[i] * bv[j];
        }
        __syncthreads();
    }

    #pragma unroll
    for (int i = 0; i < 4; i++) {
        const int o = o0 + ty * 4 + i;
        const float bi = bias[o];
        float4 r4 = make_float4(acc[i][0] + bi, acc[i][1] + bi,
                                acc[i][2] + bi, acc[i][3] + bi);
        const size_t off = ((size_t)b * O + o) * L_ + l0 + tx * 4;
        if (RES) {
            const float4 x4 = *(const float4*)(resid + off);
            r4.x += x4.x; r4.y += x4.y; r4.z += x4.z; r4.w += x4.w;
        }
        *(float4*)(out + off) = r4;
    }
}

// ---------------------------------------------------------------------------
// MFMA flash attention. Block = 256 thr (4 waves), Q-tile 128 rows, j-tile 64.
// qkv fp32 [b][768][L]; out fp32 [b][256][L].
// Wave w owns rows w*32..w*32+31 (2 m-frags). Per j-tile: 8 S-MFMAs,
// 12 PV-MFMAs (3rd n-frag = ones-column -> running softmax denominator,
// auto-rescaled with O; kills the per-iter shuffle-sum entirely).
// ---------------------------------------------------------------------------
__global__ __launch_bounds__(256) void attn_mfma(
    const float* __restrict__ qkv, float* __restrict__ out)
{
    __shared__ __align__(16) short Ks[64][40];   // [j][d] bf16, row 80B (16B-mult)
    __shared__ __align__(16) short Vt[48][72];   // [dv][j] bf16; rows 32..47: ones/zeros
    __shared__ __align__(16) short Ss[128][72];  // [i][j]  bf16 P-tile
    __shared__ __align__(16) float Ot[32][132];  // [dv][i] fp32 epilogue transpose

    const int t    = threadIdx.x;
    const int lane = t & 63;
    const int w    = t >> 6;
    const int n    = lane & 15;
    const int quad = lane >> 4;
    const int b  = blockIdx.z;
    const int h  = blockIdx.y;
    const int i0 = blockIdx.x * 128;

    const float scale = 0.17677669529663687f;  // 1/sqrt(32)
    const float* qb = qkv + ((size_t)b * 768 + h * DH_) * L_;
    const float* kb = qb + (size_t)256 * L_;
    const float* vb = qb + (size_t)512 * L_;

    // ones-row (dv=32) + zero rows 33..47, written once
    for (int idx = t; idx < 16 * 72; idx += 256) {
        int r = idx / 72, c = idx % 72;
        Vt[32 + r][c] = (r == 0) ? (short)0x3F80 : (short)0;
    }

    // Q A-frags (scale folded in). One-time scattered 4B loads, L2-resident.
    short8 qa[2];
    #pragma unroll
    for (int a = 0; a < 2; a++) {
        const int i = i0 + w * 32 + a * 16 + n;
        #pragma unroll
        for (int r = 0; r < 8; r++) {
            const int d = quad * 8 + r;
            qa[a][r] = f2bf(qb[(size_t)d * L_ + i] * scale);
        }
    }

    float m_s[2][4];
    #pragma unroll
    for (int a = 0; a < 2; a++)
        #pragma unroll
        for (int r = 0; r < 4; r++) m_s[a][r] = -INFINITY;
    f32x4 o_acc[2][3];
    #pragma unroll
    for (int a = 0; a < 2; a++)
        #pragma unroll
        for (int nf = 0; nf < 3; nf++) o_acc[a][nf] = (f32x4){0.f, 0.f, 0.f, 0.f};

    const int jj   = (t & 15) * 4;   // staging: 4 consecutive l
    const int drow = t >> 4;         // staging: d base (0..15)

    for (int j0 = 0; j0 < L_; j0 += 64) {
        __syncthreads();   // prior iter's PV done with Ks/Vt/Ss
        #pragma unroll
        for (int rr = 0; rr < 2; rr++) {
            const int d = drow + rr * 16;
            const float4 k4 = *(const float4*)&kb[(size_t)d * L_ + j0 + jj];
            Ks[jj + 0][d] = f2bf(k4.x);
            Ks[jj + 1][d] = f2bf(k4.y);
            Ks[jj + 2][d] = f2bf(k4.z);
            Ks[jj + 3][d] = f2bf(k4.w);
            const float4 v4 = *(const float4*)&vb[(size_t)d * L_ + j0 + jj];
            short4v vv = { f2bf(v4.x), f2bf(v4.y), f2bf(v4.z), f2bf(v4.w) };
            *(short4v*)&Vt[d][jj] = vv;
        }
        __syncthreads();   // staging visible

        // ---- S = Q K^T : D[m=i][n=j] ----
        short8 kf[4];
        #pragma unroll
        for (int f = 0; f < 4; f++)
            kf[f] = *(const short8*)&Ks[f * 16 + n][quad * 8];
        f32x4 s[2][4];
        #pragma unroll
        for (int a = 0; a < 2; a++)
            #pragma unroll
            for (int f = 0; f < 4; f++) {
                f32x4 z = {0.f, 0.f, 0.f, 0.f};
                s[a][f] = __builtin_amdgcn_mfma_f32_16x16x32_bf16(qa[a], kf[f], z, 0, 0, 0);
            }

        // ---- online softmax: quad-16 max reduce, ones-trick for denom ----
        #pragma unroll
        for (int a = 0; a < 2; a++) {
            #pragma unroll
            for (int r = 0; r < 4; r++) {
                float mx = fmaxf(fmaxf(s[a][0][r], s[a][1][r]),
                                 fmaxf(s[a][2][r], s[a][3][r]));
                mx = fmaxf(mx, __shfl_xor(mx, 1, 64));
                mx = fmaxf(mx, __shfl_xor(mx, 2, 64));
                mx = fmaxf(mx, __shfl_xor(mx, 4, 64));
                mx = fmaxf(mx, __shfl_xor(mx, 8, 64));
                const float mn = fmaxf(m_s[a][r], mx);
                const float al = __expf(m_s[a][r] - mn);  // 0 on first tile
                m_s[a][r] = mn;
                #pragma unroll
                for (int nf = 0; nf < 3; nf++) o_acc[a][nf][r] *= al;
                const int irow = w * 32 + a * 16 + quad * 4 + r;
                #pragma unroll
                for (int f = 0; f < 4; f++)
                    Ss[irow][f * 16 + n] = f2bf(__expf(s[a][f][r] - mn));
            }
        }
        // Ss rows of wave w written & read only by wave w -> no barrier needed
        // (HW waitcnt covers the in-wave LDS dependency).

        // ---- O += P V : D[m=i][n=dv], nf=2 accumulates the denominator ----
        #pragma unroll
        for (int kk = 0; kk < 2; kk++) {
            short8 vf[3];
            #pragma unroll
            for (int nf = 0; nf < 3; nf++)
                vf[nf] = *(const short8*)&Vt[nf * 16 + n][kk * 32 + quad * 8];
            #pragma unroll
            for (int a = 0; a < 2; a++) {
                const short8 pf = *(const short8*)&Ss[w * 32 + a * 16 + n][kk * 32 + quad * 8];
                #pragma unroll
                for (int nf = 0; nf < 3; nf++)
                    o_acc[a][nf] = __builtin_amdgcn_mfma_f32_16x16x32_bf16(
                        pf, vf[nf], o_acc[a][nf], 0, 0, 0);
            }
        }
    }

    // ---- finalize: l = o_acc[a][2][r] at col 0 of the quad; divide; store ----
    #pragma unroll
    for (int a = 0; a < 2; a++) {
        #pragma unroll
        for (int r = 0; r < 4; r++) {
            const float lv  = __shfl(o_acc[a][2][r], lane & 48, 64);
            const float inv = 1.f / lv;
            const int il = w * 32 + a * 16 + quad * 4 + r;
            Ot[n][il]      = o_acc[a][0][r] * inv;
            Ot[16 + n][il] = o_acc[a][1][r] * inv;
        }
    }
    __syncthreads();
    const int il4 = (t & 31) * 4;
    const int dvb = t >> 5;
    float* ob = out + ((size_t)b * CIN + h * DH_) * L_ + i0;
    #pragma unroll
    for (int r = 0; r < 4; r++) {
        const int dv = dvb + r * 8;
        *(float4*)&ob[(size_t)dv * L_ + il4] = *(const float4*)&Ot[dv][il4];
    }
}

// ---------------------------------------------------------------------------
extern "C" void kernel_launch(void* const* d_in, const int* in_sizes, int n_in,
                              void* d_out, int out_size, void* d_ws, size_t ws_size,
                              hipStream_t stream) {
    const float* x      = (const float*)d_in[0];
    const float* w_qkv  = (const float*)d_in[1];
    const float* b_qkv  = (const float*)d_in[2];
    const float* w_proj = (const float*)d_in[3];
    const float* b_proj = (const float*)d_in[4];
    float* out = (float*)d_out;

    float* qkv   = (float*)d_ws;                 // 24 MB fp32 [b][768][L]
    float* attno = qkv + (size_t)B_ * 768 * L_;  // 8 MB fp32 [b][256][L]

    gemm1x1<768, false><<<dim3(L_ / 64, 768 / 64, B_), 256, 0, stream>>>(
        x, w_qkv, b_qkv, nullptr, qkv);

    attn_mfma<<<dim3(L_ / 128, NH_, B_), 256, 0, stream>>>(qkv, attno);

    gemm1x1<256, true><<<dim3(L_ / 64, 256 / 64, B_), 256, 0, stream>>>(
        attno, w_proj, b_proj, x, out);
}

// Round 3
// 136.195 us; speedup vs baseline: 7.6249x; 1.5093x over previous
//
#include <hip/hip_runtime.h>
#include <math.h>

#define B_   8
#define CIN  256
#define L_   1024
#define NH_  8
#define DH_  32

typedef __attribute__((ext_vector_type(8))) short short8;
typedef __attribute__((ext_vector_type(4))) short short4v;
typedef __attribute__((ext_vector_type(4))) float f32x4;
typedef __attribute__((ext_vector_type(4))) unsigned int uint4v;
typedef __attribute__((ext_vector_type(2))) unsigned int uint2v;

__device__ inline short f2bf(float f) {
    union { float f; unsigned u; } v; v.f = f;
    return (short)((v.u + 0x7FFFu + ((v.u >> 16) & 1u)) >> 16);
}
__device__ inline unsigned pk2(float a, float b) {
    return (unsigned)(unsigned short)f2bf(a) | ((unsigned)(unsigned short)f2bf(b) << 16);
}

// ---------------------------------------------------------------------------
// x [b][256][1024] fp32 -> xT [b][1024][256] bf16  (LDS-tiled 32x32)
// ---------------------------------------------------------------------------
__global__ __launch_bounds__(256) void transpose_cast(
    const float* __restrict__ x, short* __restrict__ xT)
{
    __shared__ short Ts[32][34];
    const int t = threadIdx.x;
    const int b = blockIdx.z, c0 = blockIdx.y * 32, l0 = blockIdx.x * 32;

    const int c = t >> 3, ls = (t & 7) * 4;
    const float4 x4 = *(const float4*)&x[(((size_t)b * CIN + c0 + c) << 10) + l0 + ls];
    Ts[ls + 0][c] = f2bf(x4.x);
    Ts[ls + 1][c] = f2bf(x4.y);
    Ts[ls + 2][c] = f2bf(x4.z);
    Ts[ls + 3][c] = f2bf(x4.w);
    __syncthreads();
    const int l = t >> 3, cs = (t & 7) * 4;
    uint2v o;
    o.x = (unsigned)(unsigned short)Ts[l][cs]     | ((unsigned)(unsigned short)Ts[l][cs + 1] << 16);
    o.y = (unsigned)(unsigned short)Ts[l][cs + 2] | ((unsigned)(unsigned short)Ts[l][cs + 3] << 16);
    *(uint2v*)&xT[(((size_t)b << 10) + l0 + l) * CIN + c0 + cs] = o;
}

// ---------------------------------------------------------------------------
// QKV GEMM: qkvT[b][l][o] = sum_c xT[b][l][c] * w[o][c] + bias[o], bf16 out.
// A-frag = xT rows (m=l), B-frag = w rows (n=o). Tile 128(l) x 128(o), K=32.
// ---------------------------------------------------------------------------
__global__ __launch_bounds__(256) void qkv_gemm(
    const short* __restrict__ xT, const float* __restrict__ w,
    const float* __restrict__ bias, short* __restrict__ qkvT)
{
    __shared__ short Xs[128][40];
    __shared__ short Wt[128][40];
    const int t = threadIdx.x, lane = t & 63, wv = t >> 6;
    const int n = lane & 15, quad = lane >> 4;
    const int b = blockIdx.z, o0 = blockIdx.y * 128, l0 = blockIdx.x * 128;

    float bias_r[8];
    #pragma unroll
    for (int nf = 0; nf < 8; nf++) bias_r[nf] = bias[o0 + nf * 16 + n];

    f32x4 acc[2][8];
    #pragma unroll
    for (int a = 0; a < 2; a++)
        #pragma unroll
        for (int nf = 0; nf < 8; nf++) acc[a][nf] = (f32x4){0.f, 0.f, 0.f, 0.f};

    for (int c0 = 0; c0 < CIN; c0 += 32) {
        #pragma unroll
        for (int r = 0; r < 2; r++) {
            const int idx = t + r * 256;
            const int l = idx >> 2, cs = (idx & 3) * 8;
            *(uint4v*)&Xs[l][cs] =
                *(const uint4v*)&xT[(((size_t)b << 10) + l0 + l) * CIN + c0 + cs];
        }
        #pragma unroll
        for (int r = 0; r < 4; r++) {
            const int idx = t + r * 256;
            const int o = idx >> 3, cs = (idx & 7) * 4;
            const float4 w4 = *(const float4*)&w[(size_t)(o0 + o) * CIN + c0 + cs];
            uint2v pw; pw.x = pk2(w4.x, w4.y); pw.y = pk2(w4.z, w4.w);
            *(uint2v*)&Wt[o][cs] = pw;
        }
        __syncthreads();

        short8 af[2];
        #pragma unroll
        for (int a = 0; a < 2; a++)
            af[a] = *(const short8*)&Xs[wv * 32 + a * 16 + n][quad * 8];
        #pragma unroll
        for (int nf = 0; nf < 8; nf++) {
            const short8 bf = *(const short8*)&Wt[nf * 16 + n][quad * 8];
            #pragma unroll
            for (int a = 0; a < 2; a++)
                acc[a][nf] = __builtin_amdgcn_mfma_f32_16x16x32_bf16(af[a], bf, acc[a][nf], 0, 0, 0);
        }
        __syncthreads();
    }

    #pragma unroll
    for (int a = 0; a < 2; a++)
        #pragma unroll
        for (int reg = 0; reg < 4; reg++) {
            const size_t l = l0 + wv * 32 + a * 16 + quad * 4 + reg;
            short* row = qkvT + (((size_t)b << 10) + l) * 768 + o0 + n;
            #pragma unroll
            for (int nf = 0; nf < 8; nf++)
                row[nf * 16] = f2bf(acc[a][nf][reg] + bias_r[nf]);
        }
}

// ---------------------------------------------------------------------------
// Proj GEMM: out[b][o][l] = sum_c w[o][c]*aT[b][l][c] + bias[o] + resid[b][o][l]
// A-frag = w rows (m=o), B-frag = aT rows (n=l). Tile 64(o) x 128(l).
// ---------------------------------------------------------------------------
__global__ __launch_bounds__(256) void proj_gemm(
    const short* __restrict__ aT, const float* __restrict__ w,
    const float* __restrict__ bias, const float* __restrict__ resid,
    float* __restrict__ out)
{
    __shared__ short Xs[128][40];
    __shared__ short Wt[64][40];
    const int t = threadIdx.x, lane = t & 63, wv = t >> 6;
    const int n = lane & 15, quad = lane >> 4;
    const int b = blockIdx.z, o0 = blockIdx.y * 64, l0 = blockIdx.x * 128;

    float bias_r[4];
    #pragma unroll
    for (int reg = 0; reg < 4; reg++) bias_r[reg] = bias[o0 + wv * 16 + quad * 4 + reg];

    f32x4 acc[8];
    #pragma unroll
    for (int nf = 0; nf < 8; nf++) acc[nf] = (f32x4){0.f, 0.f, 0.f, 0.f};

    for (int c0 = 0; c0 < CIN; c0 += 32) {
        #pragma unroll
        for (int r = 0; r < 2; r++) {
            const int idx = t + r * 256;
            const int l = idx >> 2, cs = (idx & 3) * 8;
            *(uint4v*)&Xs[l][cs] =
                *(const uint4v*)&aT[(((size_t)b << 10) + l0 + l) * CIN + c0 + cs];
        }
        #pragma unroll
        for (int r = 0; r < 2; r++) {
            const int idx = t + r * 256;
            const int o = idx >> 3, cs = (idx & 7) * 4;
            const float4 w4 = *(const float4*)&w[(size_t)(o0 + o) * CIN + c0 + cs];
            uint2v pw; pw.x = pk2(w4.x, w4.y); pw.y = pk2(w4.z, w4.w);
            *(uint2v*)&Wt[o][cs] = pw;
        }
        __syncthreads();

        const short8 af = *(const short8*)&Wt[wv * 16 + n][quad * 8];
        #pragma unroll
        for (int nf = 0; nf < 8; nf++) {
            const short8 bf = *(const short8*)&Xs[nf * 16 + n][quad * 8];
            acc[nf] = __builtin_amdgcn_mfma_f32_16x16x32_bf16(af, bf, acc[nf], 0, 0, 0);
        }
        __syncthreads();
    }

    #pragma unroll
    for (int reg = 0; reg < 4; reg++) {
        const int o = o0 + wv * 16 + quad * 4 + reg;
        #pragma unroll
        for (int nf = 0; nf < 8; nf++) {
            const size_t off = (((size_t)b * CIN + o) << 10) + l0 + nf * 16 + n;
            out[off] = acc[nf][reg] + bias_r[reg] + resid[off];
        }
    }
}

// ---------------------------------------------------------------------------
// Flash attention, fixed-shift softmax (no reductions at all).
// qkvT [b][l][768] bf16: q at h*32, k at 256+h*32, v at 512+h*32.
// Block = 4 waves, Q-tile 64 (wave owns 16 rows), j-tile 64.
// p = exp2(s*K1 - K2); denominator via ones-column of V (o_acc[2]).
// ---------------------------------------------------------------------------
__global__ __launch_bounds__(256) void attn_mfma(
    const short* __restrict__ qkvT, short* __restrict__ attnoT)
{
    __shared__ short Ks[64][40];
    __shared__ short Vt[48][72];
    __shared__ __align__(16) char umem[64 * 38 * 4];   // union: Ss / OtT
    short (*Ss)[72]  = (short(*)[72])umem;             // [i][j] bf16 P
    float (*OtT)[38] = (float(*)[38])umem;             // [i][dv] fp32 epilogue

    const int t = threadIdx.x, lane = t & 63, wv = t >> 6;
    const int n = lane & 15, quad = lane >> 4;
    const int b = blockIdx.z, h = blockIdx.y, i0 = blockIdx.x * 64;

    const short* base = qkvT + ((size_t)b << 10) * 768;

    // ones row (dv=32) + zero rows 33..47
    for (int idx = t; idx < 16 * 72; idx += 256) {
        const int r = idx / 72, c = idx - r * 72;
        Vt[32 + r][c] = (r == 0) ? (short)0x3F80 : (short)0;
    }

    // Q A-frag direct from global ([l][d] layout, d-contiguous)
    const short8 qa = *(const short8*)&base[(size_t)(i0 + wv * 16 + n) * 768 + h * DH_ + quad * 8];

    f32x4 o_acc[3];
    #pragma unroll
    for (int nf = 0; nf < 3; nf++) o_acc[nf] = (f32x4){0.f, 0.f, 0.f, 0.f};

    const float K1 = 0.25503510f;    // (1/sqrt(32)) * log2(e)
    const float K2 = 11.54156036f;   // 8 * log2(e)

    for (int j0 = 0; j0 < L_; j0 += 64) {
        __syncthreads();
        {   // K stage: straight 16B row copies
            const int j = t >> 2, cs = (t & 3) * 8;
            *(uint4v*)&Ks[j][cs] =
                *(const uint4v*)&base[(size_t)(j0 + j) * 768 + 256 + h * DH_ + cs];
        }
        #pragma unroll
        for (int r = 0; r < 2; r++) {   // V stage: transpose to [dv][j]
            const int idx = t + r * 256;
            const int j = idx >> 3, ds = (idx & 7) * 4;
            const short4v v4 = *(const short4v*)&base[(size_t)(j0 + j) * 768 + 512 + h * DH_ + ds];
            Vt[ds + 0][j] = v4[0];
            Vt[ds + 1][j] = v4[1];
            Vt[ds + 2][j] = v4[2];
            Vt[ds + 3][j] = v4[3];
        }
        __syncthreads();

        // ---- S = Q K^T ----
        f32x4 s[4];
        #pragma unroll
        for (int f = 0; f < 4; f++) {
            const short8 kf = *(const short8*)&Ks[f * 16 + n][quad * 8];
            f32x4 z = {0.f, 0.f, 0.f, 0.f};
            s[f] = __builtin_amdgcn_mfma_f32_16x16x32_bf16(qa, kf, z, 0, 0, 0);
        }

        // ---- p = exp2(s*K1 - K2), write P tile (wave-private rows) ----
        #pragma unroll
        for (int f = 0; f < 4; f++)
            #pragma unroll
            for (int r = 0; r < 4; r++) {
                const int irow = wv * 16 + quad * 4 + r;
                Ss[irow][f * 16 + n] = f2bf(exp2f(fmaf(s[f][r], K1, -K2)));
            }

        // ---- O += P V (nf=2 n-frag = ones column -> denominator) ----
        #pragma unroll
        for (int kk = 0; kk < 2; kk++) {
            const short8 pf = *(const short8*)&Ss[wv * 16 + n][kk * 32 + quad * 8];
            #pragma unroll
            for (int nf = 0; nf < 3; nf++) {
                const short8 vf = *(const short8*)&Vt[nf * 16 + n][kk * 32 + quad * 8];
                o_acc[nf] = __builtin_amdgcn_mfma_f32_16x16x32_bf16(pf, vf, o_acc[nf], 0, 0, 0);
            }
        }
    }

    __syncthreads();   // all PV reads of Ss done before OtT overwrites umem
    #pragma unroll
    for (int r = 0; r < 4; r++) {
        const float lv  = __shfl(o_acc[2][r], lane & 48, 64);
        const float inv = 1.f / lv;
        const int il = wv * 16 + quad * 4 + r;
        OtT[il][n]      = o_acc[0][r] * inv;
        OtT[il][16 + n] = o_acc[1][r] * inv;
    }
    __syncthreads();
    short* ob = attnoT + (((size_t)b << 10) + i0) * CIN + h * DH_;
    #pragma unroll
    for (int r = 0; r < 2; r++) {
        const int idx = t + r * 256;
        const int l = idx >> 3, cs = (idx & 7) * 4;
        uint2v pv;
        pv.x = pk2(OtT[l][cs],     OtT[l][cs + 1]);
        pv.y = pk2(OtT[l][cs + 2], OtT[l][cs + 3]);
        *(uint2v*)&ob[(size_t)l * CIN + cs] = pv;
    }
}

// ---------------------------------------------------------------------------
extern "C" void kernel_launch(void* const* d_in, const int* in_sizes, int n_in,
                              void* d_out, int out_size, void* d_ws, size_t ws_size,
                              hipStream_t stream) {
    const float* x      = (const float*)d_in[0];
    const float* w_qkv  = (const float*)d_in[1];
    const float* b_qkv  = (const float*)d_in[2];
    const float* w_proj = (const float*)d_in[3];
    const float* b_proj = (const float*)d_in[4];
    float* out = (float*)d_out;

    short* xT     = (short*)d_ws;                          // 4 MB  [b][l][256]
    short* qkvT   = xT   + (size_t)B_ * L_ * CIN;          // 12 MB [b][l][768]
    short* attnoT = qkvT + (size_t)B_ * L_ * 768;          // 4 MB  [b][l][256]

    transpose_cast<<<dim3(32, 8, B_), 256, 0, stream>>>(x, xT);
    qkv_gemm<<<dim3(8, 6, B_), 256, 0, stream>>>(xT, w_qkv, b_qkv, qkvT);
    attn_mfma<<<dim3(16, NH_, B_), 256, 0, stream>>>(qkvT, attnoT);
    proj_gemm<<<dim3(8, 4, B_), 256, 0, stream>>>(attnoT, w_proj, b_proj, x, out);
}

// Round 5
// 130.200 us; speedup vs baseline: 7.9759x; 1.0460x over previous
//
#include <hip/hip_runtime.h>
#include <math.h>

#define B_   8
#define CIN  256
#define L_   1024
#define NH_  8
#define DH_  32

typedef __attribute__((ext_vector_type(8))) short short8;
typedef __attribute__((ext_vector_type(4))) short short4v;
typedef __attribute__((ext_vector_type(4))) float f32x4;
typedef __attribute__((ext_vector_type(4))) unsigned int uint4v;
typedef __attribute__((ext_vector_type(2))) unsigned int uint2v;

__device__ inline short f2bf_hu(float f) {       // half-up, 2 ops
    union { float f; unsigned u; } v; v.f = f;
    return (short)((v.u + 0x8000u) >> 16);
}
// pack bf16(a) | bf16(b)<<16 : 2 adds + 1 v_perm
__device__ inline unsigned pkbf2(float a, float b) {
    union { float f; unsigned u; } x, y; x.f = a; y.f = b;
    return __builtin_amdgcn_perm(y.u + 0x8000u, x.u + 0x8000u, 0x07060302u);
}

// ---------------------------------------------------------------------------
// x [b][256][1024] fp32 -> xT [b][1024][256] bf16  (LDS-tiled 32x32)
// ---------------------------------------------------------------------------
__global__ __launch_bounds__(256) void transpose_cast(
    const float* __restrict__ x, short* __restrict__ xT)
{
    __shared__ short Ts[32][34];
    const int t = threadIdx.x;
    const int b = blockIdx.z, c0 = blockIdx.y * 32, l0 = blockIdx.x * 32;

    const int c = t >> 3, ls = (t & 7) * 4;
    const float4 x4 = *(const float4*)&x[(((size_t)b * CIN + c0 + c) << 10) + l0 + ls];
    Ts[ls + 0][c] = f2bf_hu(x4.x);
    Ts[ls + 1][c] = f2bf_hu(x4.y);
    Ts[ls + 2][c] = f2bf_hu(x4.z);
    Ts[ls + 3][c] = f2bf_hu(x4.w);
    __syncthreads();
    const int l = t >> 3, cs = (t & 7) * 4;
    uint2v o;
    o.x = (unsigned)(unsigned short)Ts[l][cs]     | ((unsigned)(unsigned short)Ts[l][cs + 1] << 16);
    o.y = (unsigned)(unsigned short)Ts[l][cs + 2] | ((unsigned)(unsigned short)Ts[l][cs + 3] << 16);
    *(uint2v*)&xT[(((size_t)b << 10) + l0 + l) * CIN + c0 + cs] = o;
}

// ---------------------------------------------------------------------------
// QKV GEMM: qkvT[b][l][o] = xT[b][l][:]·w[o][:] + bias[o], bf16 out.
// Tile 64(l) x 128(o), K=32. Grid 16x6x8 = 768 blocks = 3/CU exact.
// ---------------------------------------------------------------------------
__global__ __launch_bounds__(256) void qkv_gemm(
    const short* __restrict__ xT, const float* __restrict__ w,
    const float* __restrict__ bias, short* __restrict__ qkvT)
{
    __shared__ short Xs[64][40];
    __shared__ short Wt[128][40];
    const int t = threadIdx.x, lane = t & 63, wv = t >> 6;
    const int n = lane & 15, quad = lane >> 4;
    const int b = blockIdx.z, o0 = blockIdx.y * 128, l0 = blockIdx.x * 64;

    float bias_r[8];
    #pragma unroll
    for (int nf = 0; nf < 8; nf++) bias_r[nf] = bias[o0 + nf * 16 + n];

    f32x4 acc[8];
    #pragma unroll
    for (int nf = 0; nf < 8; nf++) acc[nf] = (f32x4){0.f, 0.f, 0.f, 0.f};

    for (int c0 = 0; c0 < CIN; c0 += 32) {
        {   // X tile: 64 rows x 32 cols, one 16B copy per thread (FIXED idx)
            const int l = t >> 2, cs = (t & 3) * 8;
            *(uint4v*)&Xs[l][cs] =
                *(const uint4v*)&xT[(((size_t)b << 10) + l0 + l) * CIN + c0 + cs];
        }
        {   // W tile: 128x32, fp32 -> bf16, 16 floats per thread
            const int o = t >> 1, cs = (t & 1) * 16;
            const float* wp = &w[(size_t)(o0 + o) * CIN + c0 + cs];
            const float4 w0 = *(const float4*)(wp);
            const float4 w1 = *(const float4*)(wp + 4);
            const float4 w2 = *(const float4*)(wp + 8);
            const float4 w3 = *(const float4*)(wp + 12);
            uint4v pa = { pkbf2(w0.x, w0.y), pkbf2(w0.z, w0.w),
                          pkbf2(w1.x, w1.y), pkbf2(w1.z, w1.w) };
            uint4v pb = { pkbf2(w2.x, w2.y), pkbf2(w2.z, w2.w),
                          pkbf2(w3.x, w3.y), pkbf2(w3.z, w3.w) };
            *(uint4v*)&Wt[o][cs]     = pa;
            *(uint4v*)&Wt[o][cs + 8] = pb;
        }
        __syncthreads();

        const short8 af = *(const short8*)&Xs[wv * 16 + n][quad * 8];
        #pragma unroll
        for (int nf = 0; nf < 8; nf++) {
            const short8 bf = *(const short8*)&Wt[nf * 16 + n][quad * 8];
            acc[nf] = __builtin_amdgcn_mfma_f32_16x16x32_bf16(af, bf, acc[nf], 0, 0, 0);
        }
        __syncthreads();
    }

    #pragma unroll
    for (int reg = 0; reg < 4; reg++) {
        const size_t l = l0 + wv * 16 + quad * 4 + reg;
        short* row = qkvT + (((size_t)b << 10) + l) * 768 + o0 + n;
        #pragma unroll
        for (int nf = 0; nf < 8; nf++)
            row[nf * 16] = f2bf_hu(acc[nf][reg] + bias_r[nf]);
    }
}

// ---------------------------------------------------------------------------
// Proj GEMM: out[b][o][l] = w[o][:]·aT[b][l][:] + bias[o] + resid[b][o][l]
// Tile 64(o) x 64(l). Grid 16x4x8 = 512 blocks = 2/CU exact.
// ---------------------------------------------------------------------------
__global__ __launch_bounds__(256) void proj_gemm(
    const short* __restrict__ aT, const float* __restrict__ w,
    const float* __restrict__ bias, const float* __restrict__ resid,
    float* __restrict__ out)
{
    __shared__ short Xs[64][40];
    __shared__ short Wt[64][40];
    const int t = threadIdx.x, lane = t & 63, wv = t >> 6;
    const int n = lane & 15, quad = lane >> 4;
    const int b = blockIdx.z, o0 = blockIdx.y * 64, l0 = blockIdx.x * 64;

    float bias_r[4];
    #pragma unroll
    for (int reg = 0; reg < 4; reg++) bias_r[reg] = bias[o0 + wv * 16 + quad * 4 + reg];

    f32x4 acc[4];
    #pragma unroll
    for (int nf = 0; nf < 4; nf++) acc[nf] = (f32x4){0.f, 0.f, 0.f, 0.f};

    for (int c0 = 0; c0 < CIN; c0 += 32) {
        {   // aT tile 64x32 (FIXED idx)
            const int l = t >> 2, cs = (t & 3) * 8;
            *(uint4v*)&Xs[l][cs] =
                *(const uint4v*)&aT[(((size_t)b << 10) + l0 + l) * CIN + c0 + cs];
        }
        {   // W tile 64x32, 8 floats per thread
            const int o = t >> 2, cs = (t & 3) * 8;
            const float* wp = &w[(size_t)(o0 + o) * CIN + c0 + cs];
            const float4 a4 = *(const float4*)(wp);
            const float4 b4 = *(const float4*)(wp + 4);
            uint4v pw = { pkbf2(a4.x, a4.y), pkbf2(a4.z, a4.w),
                          pkbf2(b4.x, b4.y), pkbf2(b4.z, b4.w) };
            *(uint4v*)&Wt[o][cs] = pw;
        }
        __syncthreads();

        const short8 af = *(const short8*)&Wt[wv * 16 + n][quad * 8];
        #pragma unroll
        for (int nf = 0; nf < 4; nf++) {
            const short8 bf = *(const short8*)&Xs[nf * 16 + n][quad * 8];
            acc[nf] = __builtin_amdgcn_mfma_f32_16x16x32_bf16(af, bf, acc[nf], 0, 0, 0);
        }
        __syncthreads();
    }

    #pragma unroll
    for (int reg = 0; reg < 4; reg++) {
        const int o = o0 + wv * 16 + quad * 4 + reg;
        #pragma unroll
        for (int nf = 0; nf < 4; nf++) {
            const size_t off = (((size_t)b * CIN + o) << 10) + l0 + nf * 16 + n;
            out[off] = acc[nf][reg] + bias_r[reg] + resid[off];
        }
    }
}

// ---------------------------------------------------------------------------
// Flash attention, fixed-shift softmax, S^T-MFMA + swizzled V.
// Lane holds 4 consecutive j after S^T -> b64 P-writes with perm packing.
// Vt col-slot XOR swizzle (mask kept in-range: ((dv>>2)&7)<<3) -> conflict-
// free transpose staging; constant rows are column-uniform so the mask
// permutation is a no-op on their values. Denominator via ones-column.
// ---------------------------------------------------------------------------
__global__ __launch_bounds__(256) void attn_mfma(
    const short* __restrict__ qkvT, short* __restrict__ attnoT)
{
    __shared__ short Ks[64][40];
    __shared__ short Vt[48][80];
    __shared__ __align__(16) char umem[64 * 80 * 2];
    short (*Ss)[80] = (short(*)[80])umem;          // [i][j] bf16 P
    float (*OtT)[38] = (float(*)[38])umem;         // [i][dv] fp32 epilogue

    const int t = threadIdx.x, lane = t & 63, wv = t >> 6;
    const int n = lane & 15, quad = lane >> 4;
    const int b = blockIdx.z, h = blockIdx.y, i0 = blockIdx.x * 64;

    const short* base = qkvT + ((size_t)b << 10) * 768;

    // ones row (dv=32) + zero rows 33..47, all 80 cols
    for (int idx = t; idx < 16 * 80; idx += 256) {
        const int r = idx / 80, c = idx - r * 80;
        Vt[32 + r][c] = (r == 0) ? (short)0x3F80 : (short)0;
    }

    const short8 qa = *(const short8*)&base[(size_t)(i0 + wv * 16 + n) * 768 + h * DH_ + quad * 8];

    f32x4 o_acc[3];
    #pragma unroll
    for (int nf = 0; nf < 3; nf++) o_acc[nf] = (f32x4){0.f, 0.f, 0.f, 0.f};

    const float K1 = 0.25503510f;    // (1/sqrt(32)) * log2(e)
    const float K2 = 11.54156036f;   // 8 * log2(e)

    for (int j0 = 0; j0 < L_; j0 += 64) {
        __syncthreads();
        {   // K stage: straight 16B row copies
            const int j = t >> 2, cs = (t & 3) * 8;
            *(uint4v*)&Ks[j][cs] =
                *(const uint4v*)&base[(size_t)(j0 + j) * 768 + 256 + h * DH_ + cs];
        }
        #pragma unroll
        for (int r = 0; r < 2; r++) {   // V stage: swizzled transpose to [dv][j]
            const int idx = t + r * 256;
            const int j = idx >> 3, ds = (idx & 7) * 4;
            const short4v v4 = *(const short4v*)&base[(size_t)(j0 + j) * 768 + 512 + h * DH_ + ds];
            #pragma unroll
            for (int u = 0; u < 4; u++) {
                const int dv = ds + u;
                Vt[dv][j ^ (((dv >> 2) & 7) << 3)] = v4[u];
            }
        }
        __syncthreads();

        // ---- S^T = K Q^T : lane holds S[i = wv*16+n][j = f*16+quad*4+r] ----
        #pragma unroll
        for (int f = 0; f < 4; f++) {
            const short8 kf = *(const short8*)&Ks[f * 16 + n][quad * 8];
            f32x4 z = {0.f, 0.f, 0.f, 0.f};
            const f32x4 s = __builtin_amdgcn_mfma_f32_16x16x32_bf16(kf, qa, z, 0, 0, 0);
            const float p0 = exp2f(fmaf(s[0], K1, -K2));
            const float p1 = exp2f(fmaf(s[1], K1, -K2));
            const float p2 = exp2f(fmaf(s[2], K1, -K2));
            const float p3 = exp2f(fmaf(s[3], K1, -K2));
            uint2v pk = { pkbf2(p0, p1), pkbf2(p2, p3) };
            *(uint2v*)&Ss[wv * 16 + n][f * 16 + quad * 4] = pk;
        }
        // wave-private Ss rows: in-wave lgkmcnt ordering, no barrier needed

        // ---- O += P V (nf=2 = ones column -> denominator) ----
        #pragma unroll
        for (int kk = 0; kk < 2; kk++) {
            const short8 pf = *(const short8*)&Ss[wv * 16 + n][kk * 32 + quad * 8];
            #pragma unroll
            for (int nf = 0; nf < 3; nf++) {
                const int dv = nf * 16 + n;
                const int msk = ((dv >> 2) & 7) << 3;
                const short8 vf = *(const short8*)&Vt[dv][(kk * 32 + quad * 8) ^ msk];
                o_acc[nf] = __builtin_amdgcn_mfma_f32_16x16x32_bf16(pf, vf, o_acc[nf], 0, 0, 0);
            }
        }
    }

    __syncthreads();   // all PV reads of Ss done before OtT overwrites umem
    #pragma unroll
    for (int r = 0; r < 4; r++) {
        const float lv  = __shfl(o_acc[2][r], lane & 48, 64);
        const float inv = 1.f / lv;
        const int il = wv * 16 + quad * 4 + r;
        OtT[il][n]      = o_acc[0][r] * inv;
        OtT[il][16 + n] = o_acc[1][r] * inv;
    }
    __syncthreads();
    short* ob = attnoT + (((size_t)b << 10) + i0) * CIN + h * DH_;
    #pragma unroll
    for (int r = 0; r < 2; r++) {
        const int idx = t + r * 256;
        const int l = idx >> 3, cs = (idx & 7) * 4;
        uint2v pv;
        pv.x = pkbf2(OtT[l][cs],     OtT[l][cs + 1]);
        pv.y = pkbf2(OtT[l][cs + 2], OtT[l][cs + 3]);
        *(uint2v*)&ob[(size_t)l * CIN + cs] = pv;
    }
}

// ---------------------------------------------------------------------------
extern "C" void kernel_launch(void* const* d_in, const int* in_sizes, int n_in,
                              void* d_out, int out_size, void* d_ws, size_t ws_size,
                              hipStream_t stream) {
    const float* x      = (const float*)d_in[0];
    const float* w_qkv  = (const float*)d_in[1];
    const float* b_qkv  = (const float*)d_in[2];
    const float* w_proj = (const float*)d_in[3];
    const float* b_proj = (const float*)d_in[4];
    float* out = (float*)d_out;

    short* xT     = (short*)d_ws;                          // 4 MB  [b][l][256]
    short* qkvT   = xT   + (size_t)B_ * L_ * CIN;          // 12 MB [b][l][768]
    short* attnoT = qkvT + (size_t)B_ * L_ * 768;          // 4 MB  [b][l][256]

    transpose_cast<<<dim3(32, 8, B_), 256, 0, stream>>>(x, xT);
    qkv_gemm<<<dim3(16, 6, B_), 256, 0, stream>>>(xT, w_qkv, b_qkv, qkvT);
    attn_mfma<<<dim3(16, NH_, B_), 256, 0, stream>>>(qkvT, attnoT);
    proj_gemm<<<dim3(16, 4, B_), 256, 0, stream>>>(attnoT, w_proj, b_proj, x, out);
}